// Round 1
// baseline (508.268 us; speedup 1.0000x reference)
//
#include <hip/hip_runtime.h>
#include <hip/hip_bf16.h>
#include <math.h>

#define D_MODEL 1024
#define ATT 1024
#define NHEAD 16
#define HDIM 64
#define BATCH 2
#define SEQ 2048
#define M_ROWS (BATCH * SEQ) /* 4096 */

typedef unsigned short u16;
typedef __bf16 bf16x8 __attribute__((ext_vector_type(8)));
typedef float f4 __attribute__((ext_vector_type(4)));
typedef u16 u16x8 __attribute__((ext_vector_type(8)));
typedef u16 u16x4 __attribute__((ext_vector_type(4)));

static_assert(sizeof(u16x8) == 16, "u16x8 must be 16B");

// ---------- bf16 split helpers ----------
__device__ __forceinline__ u16 f32_to_bf16(float f) {
    union { float f; unsigned u; } c; c.f = f;
    unsigned u = c.u;
    return (u16)((u + 0x7FFFu + ((u >> 16) & 1u)) >> 16);  // RNE
}
__device__ __forceinline__ float bf16_to_f32(u16 h) {
    union { unsigned u; float f; } c; c.u = ((unsigned)h) << 16;
    return c.f;
}
__device__ __forceinline__ void split2(float f, u16& hi, u16& lo) {
    hi = f32_to_bf16(f);
    lo = f32_to_bf16(f - bf16_to_f32(hi));
}

__device__ __forceinline__ f4 mfma16(u16x8 a, u16x8 b, f4 c) {
    union U { u16x8 u; bf16x8 b; };
    U ua, ub; ua.u = a; ub.u = b;
    return __builtin_amdgcn_mfma_f32_16x16x32_bf16(ua.b, ub.b, c, 0, 0, 0);
}

// ---------- kernel 1: elementwise split of x ----------
__global__ __launch_bounds__(256) void k_split(const float* __restrict__ in,
                                               u16* __restrict__ hi,
                                               u16* __restrict__ lo, int n4) {
    int i = blockIdx.x * blockDim.x + threadIdx.x;
    if (i >= n4) return;
    const float4 v = ((const float4*)in)[i];
    float vv[4] = {v.x, v.y, v.z, v.w};
    u16 hh[4], ll[4];
#pragma unroll
    for (int j = 0; j < 4; ++j) split2(vv[j], hh[j], ll[j]);
    u16x4 hv = {hh[0], hh[1], hh[2], hh[3]};
    u16x4 lv = {ll[0], ll[1], ll[2], ll[3]};
    *(u16x4*)(hi + (size_t)i * 4) = hv;
    *(u16x4*)(lo + (size_t)i * 4) = lv;
}

// ---------- kernel 2: split + transpose a 1024x1024 weight ----------
// W[k][n] (row-major) -> WT_hi/lo[n][k]
__global__ __launch_bounds__(256) void k_splitT(const float* __restrict__ W,
                                                u16* __restrict__ hiT,
                                                u16* __restrict__ loT) {
    __shared__ float tile[32][33];
    int n0 = blockIdx.x * 32, k0 = blockIdx.y * 32;
    int tx = threadIdx.x, ty = threadIdx.y;  // (32,8)
#pragma unroll
    for (int j = 0; j < 4; ++j) {
        int r = ty + j * 8;
        tile[r][tx] = W[(size_t)(k0 + r) * ATT + n0 + tx];
    }
    __syncthreads();
#pragma unroll
    for (int j = 0; j < 4; ++j) {
        int r = ty + j * 8;              // local n
        float v = tile[tx][r];           // = W[k0+tx][n0+r]
        u16 h, l; split2(v, h, l);
        hiT[(size_t)(n0 + r) * D_MODEL + k0 + tx] = h;
        loT[(size_t)(n0 + r) * D_MODEL + k0 + tx] = l;
    }
}

// ---------- kernel 3: split-bf16 GEMM  C[M][N] = A[M][K] * B^T[N][K] + bias ----------
// 128x128 tile, 4 waves (2x2), each wave 64x64 = 4x4 fragments of 16x16x32.
template <int SPLIT_OUT>
__global__ __launch_bounds__(256) void k_gemm(
    const u16* __restrict__ Ah, const u16* __restrict__ Al,  // [M][K]
    const u16* __restrict__ Bh, const u16* __restrict__ Bl,  // [N][K]
    const float* __restrict__ bias,                          // [N]
    float* __restrict__ Co, u16* __restrict__ Ch, u16* __restrict__ Cl,
    int M, int N, int K) {
    const int LDT = 40;  // 32 + 8 pad (2-way bank conflicts only)
    __shared__ u16 Ash[128 * LDT], Asl[128 * LDT], Bsh[128 * LDT], Bsl[128 * LDT];

    int tid = threadIdx.x;
    int wave = tid >> 6, lane = tid & 63, lg = lane >> 4, ln = lane & 15;
    int wm = wave >> 1, wn = wave & 1;
    int m0 = blockIdx.y * 128, n0 = blockIdx.x * 128;

    f4 acc[4][4];
#pragma unroll
    for (int i = 0; i < 4; ++i)
#pragma unroll
        for (int j = 0; j < 4; ++j) acc[i][j] = f4{0.f, 0.f, 0.f, 0.f};

    int sr = tid >> 1, sc = (tid & 1) * 16;  // staging: row, col

    for (int kk = 0; kk < K; kk += 32) {
        const u16* gAh = Ah + (size_t)(m0 + sr) * K + kk + sc;
        const u16* gAl = Al + (size_t)(m0 + sr) * K + kk + sc;
        const u16* gBh = Bh + (size_t)(n0 + sr) * K + kk + sc;
        const u16* gBl = Bl + (size_t)(n0 + sr) * K + kk + sc;
        *(u16x8*)&Ash[sr * LDT + sc]     = *(const u16x8*)gAh;
        *(u16x8*)&Ash[sr * LDT + sc + 8] = *(const u16x8*)(gAh + 8);
        *(u16x8*)&Asl[sr * LDT + sc]     = *(const u16x8*)gAl;
        *(u16x8*)&Asl[sr * LDT + sc + 8] = *(const u16x8*)(gAl + 8);
        *(u16x8*)&Bsh[sr * LDT + sc]     = *(const u16x8*)gBh;
        *(u16x8*)&Bsh[sr * LDT + sc + 8] = *(const u16x8*)(gBh + 8);
        *(u16x8*)&Bsl[sr * LDT + sc]     = *(const u16x8*)gBl;
        *(u16x8*)&Bsl[sr * LDT + sc + 8] = *(const u16x8*)(gBl + 8);
        __syncthreads();

        u16x8 a_h[4], a_l[4], b_h[4], b_l[4];
#pragma unroll
        for (int mf = 0; mf < 4; ++mf) {
            int row = wm * 64 + mf * 16 + ln;
            a_h[mf] = *(const u16x8*)&Ash[row * LDT + lg * 8];
            a_l[mf] = *(const u16x8*)&Asl[row * LDT + lg * 8];
        }
#pragma unroll
        for (int nf = 0; nf < 4; ++nf) {
            int row = wn * 64 + nf * 16 + ln;
            b_h[nf] = *(const u16x8*)&Bsh[row * LDT + lg * 8];
            b_l[nf] = *(const u16x8*)&Bsl[row * LDT + lg * 8];
        }
#pragma unroll
        for (int mf = 0; mf < 4; ++mf)
#pragma unroll
            for (int nf = 0; nf < 4; ++nf) {
                acc[mf][nf] = mfma16(a_h[mf], b_h[nf], acc[mf][nf]);
                acc[mf][nf] = mfma16(a_h[mf], b_l[nf], acc[mf][nf]);
                acc[mf][nf] = mfma16(a_l[mf], b_h[nf], acc[mf][nf]);
            }
        __syncthreads();
    }

#pragma unroll
    for (int mf = 0; mf < 4; ++mf)
#pragma unroll
        for (int nf = 0; nf < 4; ++nf) {
            int col = n0 + wn * 64 + nf * 16 + ln;
            float bv = bias[col];
#pragma unroll
            for (int r = 0; r < 4; ++r) {
                int row = m0 + wm * 64 + mf * 16 + lg * 4 + r;
                float v = acc[mf][nf][r] + bv;
                if (SPLIT_OUT) {
                    u16 h, l; split2(v, h, l);
                    Ch[(size_t)row * N + col] = h;
                    Cl[(size_t)row * N + col] = l;
                } else {
                    Co[(size_t)row * N + col] = v;
                }
            }
        }
}

// ---------- kernel 4: flash attention (split-bf16 MFMA) ----------
// grid (qt=16, h=16, b=2), 256 threads = 4 waves; each wave owns 32 q-rows.
__global__ __launch_bounds__(256) void k_attn(
    const u16* __restrict__ Qh, const u16* __restrict__ Ql,
    const u16* __restrict__ Kh, const u16* __restrict__ Kl,
    const u16* __restrict__ Vh, const u16* __restrict__ Vl,
    u16* __restrict__ Oh, u16* __restrict__ Ol) {
    const int LDK = 72;  // 64 + 8 pad
    __shared__ u16 Ksh[64 * LDK], Ksl[64 * LDK];
    __shared__ u16 Vsh[64 * LDK], Vsl[64 * LDK];   // transposed: [d][key]
    __shared__ u16 Psh[128 * LDK], Psl[128 * LDK]; // [q_local][key]

    int tid = threadIdx.x;
    int w = tid >> 6, lane = tid & 63, lg = lane >> 4, ln = lane & 15;
    int qt = blockIdx.x, h = blockIdx.y, b = blockIdx.z;
    int q0 = qt * 128;

    // Q fragments held in registers for the whole kernel
    u16x8 qh[2][2], ql[2][2];
#pragma unroll
    for (int mf = 0; mf < 2; ++mf) {
        int row = q0 + w * 32 + mf * 16 + ln;
        const u16* pqh = Qh + (size_t)(b * SEQ + row) * ATT + h * HDIM;
        const u16* pql = Ql + (size_t)(b * SEQ + row) * ATT + h * HDIM;
#pragma unroll
        for (int ks = 0; ks < 2; ++ks) {
            qh[mf][ks] = *(const u16x8*)(pqh + ks * 32 + lg * 8);
            ql[mf][ks] = *(const u16x8*)(pql + ks * 32 + lg * 8);
        }
    }

    f4 acco[2][4];
#pragma unroll
    for (int i = 0; i < 2; ++i)
#pragma unroll
        for (int j = 0; j < 4; ++j) acco[i][j] = f4{0.f, 0.f, 0.f, 0.f};
    float run_m[2][4], run_l[2][4];
#pragma unroll
    for (int i = 0; i < 2; ++i)
#pragma unroll
        for (int r = 0; r < 4; ++r) { run_m[i][r] = -INFINITY; run_l[i][r] = 0.f; }

    int sr = tid >> 2, sc4 = (tid & 3) * 16;  // staging: key row, d col

    for (int kk = 0; kk < SEQ; kk += 64) {
        // ---- stage K (linear) and V (transposed) ----
        {
            const u16* g0 = Kh + (size_t)(b * SEQ + kk + sr) * ATT + h * HDIM + sc4;
            const u16* g1 = Kl + (size_t)(b * SEQ + kk + sr) * ATT + h * HDIM + sc4;
            *(u16x8*)&Ksh[sr * LDK + sc4]     = *(const u16x8*)g0;
            *(u16x8*)&Ksh[sr * LDK + sc4 + 8] = *(const u16x8*)(g0 + 8);
            *(u16x8*)&Ksl[sr * LDK + sc4]     = *(const u16x8*)g1;
            *(u16x8*)&Ksl[sr * LDK + sc4 + 8] = *(const u16x8*)(g1 + 8);

            const u16* gv0 = Vh + (size_t)(b * SEQ + kk + sr) * ATT + h * HDIM + sc4;
            const u16* gv1 = Vl + (size_t)(b * SEQ + kk + sr) * ATT + h * HDIM + sc4;
            u16x8 a0 = *(const u16x8*)gv0, a1 = *(const u16x8*)(gv0 + 8);
            u16x8 c0 = *(const u16x8*)gv1, c1 = *(const u16x8*)(gv1 + 8);
#pragma unroll
            for (int j = 0; j < 8; ++j) {
                Vsh[(sc4 + j) * LDK + sr] = a0[j];
                Vsh[(sc4 + 8 + j) * LDK + sr] = a1[j];
                Vsl[(sc4 + j) * LDK + sr] = c0[j];
                Vsl[(sc4 + 8 + j) * LDK + sr] = c1[j];
            }
        }
        __syncthreads();

        // ---- scores S = Q K^T / 8 ----
        f4 s[2][4];
#pragma unroll
        for (int i = 0; i < 2; ++i)
#pragma unroll
            for (int j = 0; j < 4; ++j) s[i][j] = f4{0.f, 0.f, 0.f, 0.f};
#pragma unroll
        for (int nf = 0; nf < 4; ++nf) {
#pragma unroll
            for (int ks = 0; ks < 2; ++ks) {
                u16x8 bh = *(const u16x8*)&Ksh[(nf * 16 + ln) * LDK + ks * 32 + lg * 8];
                u16x8 bl = *(const u16x8*)&Ksl[(nf * 16 + ln) * LDK + ks * 32 + lg * 8];
#pragma unroll
                for (int mf = 0; mf < 2; ++mf) {
                    s[mf][nf] = mfma16(qh[mf][ks], bh, s[mf][nf]);
                    s[mf][nf] = mfma16(qh[mf][ks], bl, s[mf][nf]);
                    s[mf][nf] = mfma16(ql[mf][ks], bh, s[mf][nf]);
                }
            }
        }
#pragma unroll
        for (int i = 0; i < 2; ++i)
#pragma unroll
            for (int j = 0; j < 4; ++j) s[i][j] = s[i][j] * 0.125f;

        // ---- online softmax; write split-P to LDS ----
#pragma unroll
        for (int mf = 0; mf < 2; ++mf) {
#pragma unroll
            for (int r = 0; r < 4; ++r) {
                float mx = fmaxf(fmaxf(s[mf][0][r], s[mf][1][r]),
                                 fmaxf(s[mf][2][r], s[mf][3][r]));
#pragma unroll
                for (int d = 1; d < 16; d <<= 1) mx = fmaxf(mx, __shfl_xor(mx, d));
                float nm = fmaxf(run_m[mf][r], mx);
                float corr = __expf(run_m[mf][r] - nm);
                int qrow = w * 32 + mf * 16 + lg * 4 + r;
                float rs = 0.f;
#pragma unroll
                for (int nf = 0; nf < 4; ++nf) {
                    float p = __expf(s[mf][nf][r] - nm);
                    rs += p;
                    u16 ph, pl; split2(p, ph, pl);
                    Psh[qrow * LDK + nf * 16 + ln] = ph;
                    Psl[qrow * LDK + nf * 16 + ln] = pl;
                }
#pragma unroll
                for (int d = 1; d < 16; d <<= 1) rs += __shfl_xor(rs, d);
                run_l[mf][r] = run_l[mf][r] * corr + rs;
                run_m[mf][r] = nm;
#pragma unroll
                for (int nf = 0; nf < 4; ++nf) acco[mf][nf][r] *= corr;
            }
        }
        __syncthreads();

        // ---- O += P V ----
#pragma unroll
        for (int ks = 0; ks < 2; ++ks) {
            u16x8 ph[2], pl[2];
#pragma unroll
            for (int mf = 0; mf < 2; ++mf) {
                ph[mf] = *(const u16x8*)&Psh[(w * 32 + mf * 16 + ln) * LDK + ks * 32 + lg * 8];
                pl[mf] = *(const u16x8*)&Psl[(w * 32 + mf * 16 + ln) * LDK + ks * 32 + lg * 8];
            }
#pragma unroll
            for (int nf = 0; nf < 4; ++nf) {
                u16x8 vh = *(const u16x8*)&Vsh[(nf * 16 + ln) * LDK + ks * 32 + lg * 8];
                u16x8 vl = *(const u16x8*)&Vsl[(nf * 16 + ln) * LDK + ks * 32 + lg * 8];
#pragma unroll
                for (int mf = 0; mf < 2; ++mf) {
                    acco[mf][nf] = mfma16(ph[mf], vh, acco[mf][nf]);
                    acco[mf][nf] = mfma16(ph[mf], vl, acco[mf][nf]);
                    acco[mf][nf] = mfma16(pl[mf], vh, acco[mf][nf]);
                }
            }
        }
        __syncthreads();
    }

    // ---- epilogue: O /= l, split-write ----
#pragma unroll
    for (int mf = 0; mf < 2; ++mf)
#pragma unroll
        for (int nf = 0; nf < 4; ++nf) {
            int col = h * HDIM + nf * 16 + ln;
#pragma unroll
            for (int r = 0; r < 4; ++r) {
                int row = q0 + w * 32 + mf * 16 + lg * 4 + r;
                float v = acco[mf][nf][r] / run_l[mf][r];
                u16 hh, ll; split2(v, hh, ll);
                Oh[(size_t)(b * SEQ + row) * ATT + col] = hh;
                Ol[(size_t)(b * SEQ + row) * ATT + col] = ll;
            }
        }
}

// ---------- launcher ----------
extern "C" void kernel_launch(void* const* d_in, const int* in_sizes, int n_in,
                              void* d_out, int out_size, void* d_ws, size_t ws_size,
                              hipStream_t stream) {
    const float* x  = (const float*)d_in[0];
    const float* Wq = (const float*)d_in[1];
    const float* bq = (const float*)d_in[2];
    const float* Wk = (const float*)d_in[3];
    const float* bk = (const float*)d_in[4];
    const float* Wv = (const float*)d_in[5];
    const float* bv = (const float*)d_in[6];
    const float* Wo = (const float*)d_in[7];
    const float* bo = (const float*)d_in[8];
    float* out = (float*)d_out;

    const size_t MK = (size_t)M_ROWS * ATT;  // 4M elems
    const size_t WE = (size_t)D_MODEL * ATT; // 1M elems

    char* p = (char*)d_ws;
    auto alloc = [&](size_t bytes) -> u16* {
        u16* r = (u16*)p;
        p += (bytes + 255) & ~(size_t)255;
        return r;
    };
    u16* x_hi = alloc(MK * 2); u16* x_lo = alloc(MK * 2);
    u16* wqT_h = alloc(WE * 2); u16* wqT_l = alloc(WE * 2);
    u16* wkT_h = alloc(WE * 2); u16* wkT_l = alloc(WE * 2);
    u16* wvT_h = alloc(WE * 2); u16* wvT_l = alloc(WE * 2);
    u16* woT_h = alloc(WE * 2); u16* woT_l = alloc(WE * 2);
    u16* q_h = alloc(MK * 2); u16* q_l = alloc(MK * 2);
    u16* k_h = alloc(MK * 2); u16* k_l = alloc(MK * 2);
    u16* v_h = alloc(MK * 2); u16* v_l = alloc(MK * 2);
    // attention output reuses the x buffers (x is dead after the QKV GEMMs)
    u16* at_h = x_hi; u16* at_l = x_lo;

    k_split<<<dim3((unsigned)(MK / 4 / 256)), 256, 0, stream>>>(x, x_hi, x_lo, (int)(MK / 4));

    dim3 bt(32, 8), gt(32, 32);
    k_splitT<<<gt, bt, 0, stream>>>(Wq, wqT_h, wqT_l);
    k_splitT<<<gt, bt, 0, stream>>>(Wk, wkT_h, wkT_l);
    k_splitT<<<gt, bt, 0, stream>>>(Wv, wvT_h, wvT_l);
    k_splitT<<<gt, bt, 0, stream>>>(Wo, woT_h, woT_l);

    dim3 gg(ATT / 128, M_ROWS / 128);  // (8, 32)
    k_gemm<1><<<gg, 256, 0, stream>>>(x_hi, x_lo, wqT_h, wqT_l, bq, nullptr, q_h, q_l,
                                      M_ROWS, ATT, D_MODEL);
    k_gemm<1><<<gg, 256, 0, stream>>>(x_hi, x_lo, wkT_h, wkT_l, bk, nullptr, k_h, k_l,
                                      M_ROWS, ATT, D_MODEL);
    k_gemm<1><<<gg, 256, 0, stream>>>(x_hi, x_lo, wvT_h, wvT_l, bv, nullptr, v_h, v_l,
                                      M_ROWS, ATT, D_MODEL);

    dim3 ga(SEQ / 128, NHEAD, BATCH);  // (16, 16, 2)
    k_attn<<<ga, 256, 0, stream>>>(q_h, q_l, k_h, k_l, v_h, v_l, at_h, at_l);

    k_gemm<0><<<gg, 256, 0, stream>>>(at_h, at_l, woT_h, woT_l, bo, out, nullptr, nullptr,
                                      M_ROWS, D_MODEL, ATT);
}

// Round 2
// 399.731 us; speedup vs baseline: 1.2715x; 1.2715x over previous
//
#include <hip/hip_runtime.h>
#include <hip/hip_bf16.h>
#include <math.h>

#define D_MODEL 1024
#define ATT 1024
#define NHEAD 16
#define HDIM 64
#define BATCH 2
#define SEQ 2048
#define M_ROWS (BATCH * SEQ) /* 4096 */

typedef unsigned short u16;
typedef unsigned int u32;
typedef __bf16 bf16x8 __attribute__((ext_vector_type(8)));
typedef float f4 __attribute__((ext_vector_type(4)));
typedef u16 u16x8 __attribute__((ext_vector_type(8)));
typedef u16 u16x4 __attribute__((ext_vector_type(4)));

static_assert(sizeof(u16x8) == 16, "u16x8 must be 16B");

// ---------- bf16 split helpers ----------
__device__ __forceinline__ u16 f32_to_bf16(float f) {
    union { float f; unsigned u; } c; c.f = f;
    unsigned u = c.u;
    return (u16)((u + 0x7FFFu + ((u >> 16) & 1u)) >> 16);  // RNE
}
__device__ __forceinline__ float bf16_to_f32(u16 h) {
    union { unsigned u; float f; } c; c.u = ((unsigned)h) << 16;
    return c.f;
}
__device__ __forceinline__ void split2(float f, u16& hi, u16& lo) {
    hi = f32_to_bf16(f);
    lo = f32_to_bf16(f - bf16_to_f32(hi));
}

__device__ __forceinline__ f4 mfma16(u16x8 a, u16x8 b, f4 c) {
    union U { u16x8 u; bf16x8 b; };
    U ua, ub; ua.u = a; ub.u = b;
    return __builtin_amdgcn_mfma_f32_16x16x32_bf16(ua.b, ub.b, c, 0, 0, 0);
}

// async global->LDS, 16B per lane, dest = uniform base + lane*16
__device__ __forceinline__ void gload16(const void* g, void* l) {
    __builtin_amdgcn_global_load_lds(
        (const __attribute__((address_space(1))) void*)g,
        (__attribute__((address_space(3))) void*)l, 16, 0, 0);
}

// ---------- kernel 1: elementwise split of x ----------
__global__ __launch_bounds__(256) void k_split(const float* __restrict__ in,
                                               u16* __restrict__ hi,
                                               u16* __restrict__ lo, int n4) {
    int i = blockIdx.x * blockDim.x + threadIdx.x;
    if (i >= n4) return;
    const float4 v = ((const float4*)in)[i];
    float vv[4] = {v.x, v.y, v.z, v.w};
    u16 hh[4], ll[4];
#pragma unroll
    for (int j = 0; j < 4; ++j) split2(vv[j], hh[j], ll[j]);
    u16x4 hv = {hh[0], hh[1], hh[2], hh[3]};
    u16x4 lv = {ll[0], ll[1], ll[2], ll[3]};
    *(u16x4*)(hi + (size_t)i * 4) = hv;
    *(u16x4*)(lo + (size_t)i * 4) = lv;
}

// ---------- kernel 2: split + transpose a 1024x1024 weight ----------
__global__ __launch_bounds__(256) void k_splitT(const float* __restrict__ W,
                                                u16* __restrict__ hiT,
                                                u16* __restrict__ loT) {
    __shared__ float tile[32][33];
    int n0 = blockIdx.x * 32, k0 = blockIdx.y * 32;
    int tx = threadIdx.x, ty = threadIdx.y;  // (32,8)
#pragma unroll
    for (int j = 0; j < 4; ++j) {
        int r = ty + j * 8;
        tile[r][tx] = W[(size_t)(k0 + r) * ATT + n0 + tx];
    }
    __syncthreads();
#pragma unroll
    for (int j = 0; j < 4; ++j) {
        int r = ty + j * 8;              // local n
        float v = tile[tx][r];           // = W[k0+tx][n0+r]
        u16 h, l; split2(v, h, l);
        hiT[(size_t)(n0 + r) * D_MODEL + k0 + tx] = h;
        loT[(size_t)(n0 + r) * D_MODEL + k0 + tx] = l;
    }
}

// ---------- kernel 2b: u16 tiled transpose (for V^T), z selects hi/lo ----------
__global__ __launch_bounds__(256) void k_transpose(
    const u16* __restrict__ src_h, const u16* __restrict__ src_l,
    u16* __restrict__ dst_h, u16* __restrict__ dst_l, int srcld, int dstld) {
    __shared__ u16 t[64][72];
    const u16* src = blockIdx.z ? src_l : src_h;
    u16* dst = blockIdx.z ? dst_l : dst_h;
    int n0 = blockIdx.x * 64, m0 = blockIdx.y * 64;
    int tid = threadIdx.x;
    int r = tid >> 2, c16 = (tid & 3) * 16;
    *(u16x8*)&t[r][c16]     = *(const u16x8*)&src[(size_t)(m0 + r) * srcld + n0 + c16];
    *(u16x8*)&t[r][c16 + 8] = *(const u16x8*)&src[(size_t)(m0 + r) * srcld + n0 + c16 + 8];
    __syncthreads();
    u16x8 o0, o1;
#pragma unroll
    for (int j = 0; j < 8; ++j) { o0[j] = t[c16 + j][r]; o1[j] = t[c16 + 8 + j][r]; }
    *(u16x8*)&dst[(size_t)(n0 + r) * dstld + m0 + c16]     = o0;
    *(u16x8*)&dst[(size_t)(n0 + r) * dstld + m0 + c16 + 8] = o1;
}

// ---------- kernel 3: split-bf16 GEMM via global_load_lds + XOR swizzle ----------
// C[M][N] = A[M][K] * B^T[N][K] + bias.  BM = MF*32, BN = 128, BK = 32.
// LDS linear, 64B rows; swizzle: 16B block cb' = cb ^ ((row>>1)&3) (both sides).
template <int MF, int SPLIT_OUT>
__global__ __launch_bounds__(256) void k_gemm(
    const u16* __restrict__ Ah, const u16* __restrict__ Al,
    const u16* __restrict__ Bh, const u16* __restrict__ Bl,
    const float* __restrict__ bq, const float* __restrict__ bk,
    const float* __restrict__ bv,
    float* __restrict__ Co, u16* __restrict__ Ch, u16* __restrict__ Cl,
    int M, int N, int K, int NBX) {
    constexpr int BM = MF * 32;
    constexpr int SAe = BM * 32;               // elems per A buffer
    constexpr int NCH = (2 * BM + 256) / 16;   // 1KB chunks per K-step
    constexpr int CPW = NCH / 4;
    __shared__ u16 sh[(2 * BM + 256) * 32];

    int tid = threadIdx.x;
    int wave = tid >> 6, lane = tid & 63, lg = lane >> 4, ln = lane & 15;
    int wm = wave >> 1, wn = wave & 1;

    int nb = gridDim.x;
    int bs = (blockIdx.x & 7) * (nb >> 3) + (blockIdx.x >> 3);  // XCD-chunked
    int bx = bs % NBX, by = bs / NBX;
    int m0 = by * BM, n0 = bx * 128;

    f4 acc[MF][4];
#pragma unroll
    for (int i = 0; i < MF; ++i)
#pragma unroll
        for (int j = 0; j < 4; ++j) acc[i][j] = f4{0.f, 0.f, 0.f, 0.f};

    for (int kk = 0; kk < K; kk += 32) {
#pragma unroll
        for (int j = 0; j < CPW; ++j) {
            int c = wave * CPW + j;
            int bo = c << 10;  // byte offset into sh (wave-uniform)
            const u16* base; int local, r0;
            if (bo < BM * 64)                { base = Ah; local = bo;                 r0 = m0; }
            else if (bo < 2 * BM * 64)       { base = Al; local = bo - BM * 64;       r0 = m0; }
            else if (bo < 2 * BM * 64 + 8192){ base = Bh; local = bo - 2 * BM * 64;   r0 = n0; }
            else                             { base = Bl; local = bo - 2 * BM * 64 - 8192; r0 = n0; }
            int lo2 = local + lane * 16;
            int row = lo2 >> 6;
            int cb  = (lo2 >> 4) & 3;
            int cbs = cb ^ ((row >> 1) & 3);      // inverse-swizzled SOURCE
            gload16(base + (size_t)(r0 + row) * K + kk + cbs * 8, (char*)sh + bo);
        }
        __syncthreads();

        u16x8 a_h[MF], a_l[MF], b_h[4], b_l[4];
#pragma unroll
        for (int mf = 0; mf < MF; ++mf) {
            int row = wm * (MF * 16) + mf * 16 + ln;
            int off = row * 32 + ((lg ^ ((row >> 1) & 3)) << 3);  // swizzled READ
            a_h[mf] = *(const u16x8*)&sh[off];
            a_l[mf] = *(const u16x8*)&sh[SAe + off];
        }
#pragma unroll
        for (int nf = 0; nf < 4; ++nf) {
            int row = wn * 64 + nf * 16 + ln;
            int off = row * 32 + ((lg ^ ((row >> 1) & 3)) << 3);
            b_h[nf] = *(const u16x8*)&sh[2 * SAe + off];
            b_l[nf] = *(const u16x8*)&sh[2 * SAe + 4096 + off];
        }
#pragma unroll
        for (int mf = 0; mf < MF; ++mf)
#pragma unroll
            for (int nf = 0; nf < 4; ++nf) {
                acc[mf][nf] = mfma16(a_h[mf], b_h[nf], acc[mf][nf]);
                acc[mf][nf] = mfma16(a_h[mf], b_l[nf], acc[mf][nf]);
                acc[mf][nf] = mfma16(a_l[mf], b_h[nf], acc[mf][nf]);
            }
        __syncthreads();
    }

#pragma unroll
    for (int mf = 0; mf < MF; ++mf)
#pragma unroll
        for (int nf = 0; nf < 4; ++nf) {
            int col = n0 + wn * 64 + nf * 16 + ln;
            float bb;
            if (bk) bb = col < 1024 ? bq[col] : (col < 2048 ? bk[col - 1024] : bv[col - 2048]);
            else    bb = bq[col];
#pragma unroll
            for (int r = 0; r < 4; ++r) {
                int row = m0 + wm * (MF * 16) + mf * 16 + lg * 4 + r;
                float v = acc[mf][nf][r] + bb;
                if (SPLIT_OUT) {
                    u16 h, l; split2(v, h, l);
                    Ch[(size_t)row * N + col] = h;
                    Cl[(size_t)row * N + col] = l;
                } else {
                    Co[(size_t)row * N + col] = v;
                }
            }
        }
}

// ---------- kernel 4: flash attention ----------
// Q/K from fused qkv [M][3072]; V pre-transposed vt [ATT][M_ROWS].
// LDS (u16 elems): Kh[0,4096) Kl[4096) Vh[8192) Vl[12288) P[16384,24576)
// 128B rows, swizzle kb' = kb ^ (row&7) everywhere.
__global__ __launch_bounds__(256) void k_attn(
    const u16* __restrict__ qkv_h, const u16* __restrict__ qkv_l,
    const u16* __restrict__ vt_h, const u16* __restrict__ vt_l,
    u16* __restrict__ Oh, u16* __restrict__ Ol) {
    __shared__ u16 sh[24576];
    int tid = threadIdx.x;
    int w = tid >> 6, lane = tid & 63, lg = lane >> 4, ln = lane & 15;

    int bs = (blockIdx.x & 7) * 64 + (blockIdx.x >> 3);  // XCD-chunked
    int qt = bs & 15, h = (bs >> 4) & 15, b = bs >> 8;
    int q0 = qt * 128;

    // Q fragments in registers
    u16x8 qh[2][2], ql[2][2];
#pragma unroll
    for (int mf = 0; mf < 2; ++mf) {
        int row = q0 + w * 32 + mf * 16 + ln;
        const u16* ph_ = qkv_h + (size_t)(b * SEQ + row) * 3072 + h * HDIM;
        const u16* pl_ = qkv_l + (size_t)(b * SEQ + row) * 3072 + h * HDIM;
#pragma unroll
        for (int ks = 0; ks < 2; ++ks) {
            qh[mf][ks] = *(const u16x8*)(ph_ + ks * 32 + lg * 8);
            ql[mf][ks] = *(const u16x8*)(pl_ + ks * 32 + lg * 8);
        }
    }

    f4 acco[2][4];
#pragma unroll
    for (int i = 0; i < 2; ++i)
#pragma unroll
        for (int j = 0; j < 4; ++j) acco[i][j] = f4{0.f, 0.f, 0.f, 0.f};
    float run_m[2][4], run_l[2][4];
#pragma unroll
    for (int i = 0; i < 2; ++i)
#pragma unroll
        for (int r = 0; r < 4; ++r) { run_m[i][r] = -INFINITY; run_l[i][r] = 0.f; }

    const u16* Kh_base = qkv_h + (size_t)(b * SEQ) * 3072 + 1024 + h * HDIM;
    const u16* Kl_base = qkv_l + (size_t)(b * SEQ) * 3072 + 1024 + h * HDIM;
    const u16* Vh_base = vt_h + (size_t)(h * HDIM) * M_ROWS + b * SEQ;
    const u16* Vl_base = vt_l + (size_t)(h * HDIM) * M_ROWS + b * SEQ;

    for (int kk = 0; kk < SEQ; kk += 64) {
        // stage K hi/lo + V^T hi/lo, 8KB each, via global_load_lds
#pragma unroll
        for (int j = 0; j < 8; ++j) {
            int c = w * 8 + j;
            int bo = c << 10;
            int buf = bo >> 13;
            int local = bo & 8191;
            int lo2 = local + lane * 16;
            int row = lo2 >> 7;       // 0..63
            int kb  = (lo2 >> 4) & 7;
            int kbs = kb ^ (row & 7); // inverse-swizzled source
            const u16* g;
            if (buf == 0)      g = Kh_base + (size_t)(kk + row) * 3072 + kbs * 8;
            else if (buf == 1) g = Kl_base + (size_t)(kk + row) * 3072 + kbs * 8;
            else if (buf == 2) g = Vh_base + (size_t)row * M_ROWS + kk + kbs * 8;
            else               g = Vl_base + (size_t)row * M_ROWS + kk + kbs * 8;
            gload16(g, (char*)sh + bo);
        }
        __syncthreads();

        // ---- S = Q K^T / 8 ----
        f4 s[2][4];
#pragma unroll
        for (int i = 0; i < 2; ++i)
#pragma unroll
            for (int j = 0; j < 4; ++j) s[i][j] = f4{0.f, 0.f, 0.f, 0.f};
#pragma unroll
        for (int nf = 0; nf < 4; ++nf) {
            int krow = nf * 16 + ln;
#pragma unroll
            for (int ks = 0; ks < 2; ++ks) {
                int off = krow * 64 + (((4 * ks + lg) ^ (krow & 7)) << 3);
                u16x8 bh = *(const u16x8*)&sh[off];
                u16x8 bl = *(const u16x8*)&sh[4096 + off];
#pragma unroll
                for (int mf = 0; mf < 2; ++mf) {
                    s[mf][nf] = mfma16(qh[mf][ks], bh, s[mf][nf]);
                    s[mf][nf] = mfma16(qh[mf][ks], bl, s[mf][nf]);
                    s[mf][nf] = mfma16(ql[mf][ks], bh, s[mf][nf]);
                }
            }
        }
#pragma unroll
        for (int i = 0; i < 2; ++i)
#pragma unroll
            for (int j = 0; j < 4; ++j) s[i][j] = s[i][j] * 0.125f;

        // ---- online softmax; P (bf16 hi only) to LDS, wave-private rows ----
#pragma unroll
        for (int mf = 0; mf < 2; ++mf) {
#pragma unroll
            for (int r = 0; r < 4; ++r) {
                float mx = fmaxf(fmaxf(s[mf][0][r], s[mf][1][r]),
                                 fmaxf(s[mf][2][r], s[mf][3][r]));
#pragma unroll
                for (int d = 1; d < 16; d <<= 1) mx = fmaxf(mx, __shfl_xor(mx, d));
                float nm = fmaxf(run_m[mf][r], mx);
                float corr = __expf(run_m[mf][r] - nm);
                int qrow = w * 32 + mf * 16 + lg * 4 + r;
                int swz = qrow & 7;
                float rs = 0.f;
#pragma unroll
                for (int nf = 0; nf < 4; ++nf) {
                    float p = __expf(s[mf][nf][r] - nm);
                    u16 ph = f32_to_bf16(p);
                    rs += bf16_to_f32(ph);  // denominator consistent with stored P
                    int key = nf * 16 + ln;
                    sh[16384 + qrow * 64 + (((key >> 3) ^ swz) << 3) + (key & 7)] = ph;
                }
#pragma unroll
                for (int d = 1; d < 16; d <<= 1) rs += __shfl_xor(rs, d);
                run_l[mf][r] = run_l[mf][r] * corr + rs;
                run_m[mf][r] = nm;
#pragma unroll
                for (int nf = 0; nf < 4; ++nf) acco[mf][nf][r] *= corr;
            }
        }
        // P is wave-private (written & read by same wave) -> no barrier needed

        // ---- O += P V ----
#pragma unroll
        for (int ks = 0; ks < 2; ++ks) {
            u16x8 pa[2];
#pragma unroll
            for (int mf = 0; mf < 2; ++mf) {
                int prow = w * 32 + mf * 16 + ln;
                pa[mf] = *(const u16x8*)&sh[16384 + prow * 64 + (((4 * ks + lg) ^ (ln & 7)) << 3)];
            }
#pragma unroll
            for (int nf = 0; nf < 4; ++nf) {
                int vrow = nf * 16 + ln;
                int off = vrow * 64 + (((4 * ks + lg) ^ (vrow & 7)) << 3);
                u16x8 vh = *(const u16x8*)&sh[8192 + off];
                u16x8 vl = *(const u16x8*)&sh[12288 + off];
#pragma unroll
                for (int mf = 0; mf < 2; ++mf) {
                    acco[mf][nf] = mfma16(pa[mf], vh, acco[mf][nf]);
                    acco[mf][nf] = mfma16(pa[mf], vl, acco[mf][nf]);
                }
            }
        }
        __syncthreads();
    }

    // ---- epilogue ----
#pragma unroll
    for (int mf = 0; mf < 2; ++mf)
#pragma unroll
        for (int nf = 0; nf < 4; ++nf) {
            int col = h * HDIM + nf * 16 + ln;
#pragma unroll
            for (int r = 0; r < 4; ++r) {
                int row = q0 + w * 32 + mf * 16 + lg * 4 + r;
                float v = acco[mf][nf][r] / run_l[mf][r];
                u16 hh, ll; split2(v, hh, ll);
                Oh[(size_t)(b * SEQ + row) * ATT + col] = hh;
                Ol[(size_t)(b * SEQ + row) * ATT + col] = ll;
            }
        }
}

// ---------- launcher ----------
extern "C" void kernel_launch(void* const* d_in, const int* in_sizes, int n_in,
                              void* d_out, int out_size, void* d_ws, size_t ws_size,
                              hipStream_t stream) {
    const float* x  = (const float*)d_in[0];
    const float* Wq = (const float*)d_in[1];
    const float* bq = (const float*)d_in[2];
    const float* Wk = (const float*)d_in[3];
    const float* bk = (const float*)d_in[4];
    const float* Wv = (const float*)d_in[5];
    const float* bv = (const float*)d_in[6];
    const float* Wo = (const float*)d_in[7];
    const float* bo = (const float*)d_in[8];
    float* out = (float*)d_out;

    const size_t MK = (size_t)M_ROWS * ATT;   // 4M elems
    const size_t WE = (size_t)D_MODEL * ATT;  // 1M elems
    const size_t M3 = (size_t)M_ROWS * 3072;  // fused qkv elems

    char* p = (char*)d_ws;
    auto alloc = [&](size_t bytes) -> u16* {
        u16* r = (u16*)p;
        p += (bytes + 255) & ~(size_t)255;
        return r;
    };
    u16* x_hi  = alloc(MK * 2); u16* x_lo  = alloc(MK * 2);
    u16* wT_h  = alloc(3 * WE * 2); u16* wT_l  = alloc(3 * WE * 2);  // [Wq;Wk;Wv]^T stacked
    u16* woT_h = alloc(WE * 2); u16* woT_l = alloc(WE * 2);
    u16* qkv_h = alloc(M3 * 2); u16* qkv_l = alloc(M3 * 2);          // [M][3072]
    u16* vt_h  = alloc(MK * 2); u16* vt_l  = alloc(MK * 2);          // V^T [1024][4096]
    u16* at_h = x_hi; u16* at_l = x_lo;  // attention out reuses x buffers

    k_split<<<dim3((unsigned)(MK / 4 / 256)), 256, 0, stream>>>(x, x_hi, x_lo, (int)(MK / 4));

    dim3 bt(32, 8), gt(32, 32);
    k_splitT<<<gt, bt, 0, stream>>>(Wq, wT_h, wT_l);
    k_splitT<<<gt, bt, 0, stream>>>(Wk, wT_h + WE, wT_l + WE);
    k_splitT<<<gt, bt, 0, stream>>>(Wv, wT_h + 2 * WE, wT_l + 2 * WE);
    k_splitT<<<gt, bt, 0, stream>>>(Wo, woT_h, woT_l);

    // fused QKV: [4096 x 3072] = x[4096x1024] @ [Wq|Wk|Wv], 768 blocks (3/CU)
    k_gemm<4, 1><<<768, 256, 0, stream>>>(x_hi, x_lo, wT_h, wT_l, bq, bk, bv,
                                          nullptr, qkv_h, qkv_l, M_ROWS, 3072, 1024, 24);

    // V^T: qkv cols [2048,3072) -> vt [1024][4096]
    k_transpose<<<dim3(16, 64, 2), 256, 0, stream>>>(qkv_h + 2048, qkv_l + 2048,
                                                     vt_h, vt_l, 3072, M_ROWS);

    k_attn<<<512, 256, 0, stream>>>(qkv_h, qkv_l, vt_h, vt_l, at_h, at_l);

    // Wo: BM=64 -> 512 blocks (2/CU)
    k_gemm<2, 0><<<512, 256, 0, stream>>>(at_h, at_l, woT_h, woT_l, bo, nullptr, nullptr,
                                          out, nullptr, nullptr, M_ROWS, 1024, 1024, 8);
}